// Round 7
// baseline (461.152 us; speedup 1.0000x reference)
//
#include <hip/hip_runtime.h>

// Fused axial attention (RoadTransformer), bf16 LDS / fp32 compute.
// R7: ONE 1024-thread block (16 waves) per b, 1 block/CU (LDS-enforced).
//     Restores R3's lockstep/L2-combining for the scatter stores (R4-6's
//     2 blk/CU thrashed L2: WRITE 940MB) while doubling waves/SIMD to 4.
//     P1: 16 outs/wave; P3: 8 groups x 2 waves; P4: 8 groups x 2 ch-halves.

typedef unsigned int u32;

__device__ __forceinline__ float blo(u32 u) { return __uint_as_float(u << 16); }
__device__ __forceinline__ float bhi(u32 u) { return __uint_as_float(u & 0xffff0000u); }
__device__ __forceinline__ unsigned short f2bf(float f) {
  const u32 u = __float_as_uint(f);
  return (unsigned short)((u + 0x7fffu + ((u >> 16) & 1u)) >> 16);   // RNE
}
__device__ __forceinline__ u32 pk2(float a, float b) {
  return (u32)f2bf(a) | ((u32)f2bf(b) << 16);
}
#define UNPK(u4, f) { f[0]=blo((u4).x); f[1]=bhi((u4).x); f[2]=blo((u4).y); f[3]=bhi((u4).y); \
                      f[4]=blo((u4).z); f[5]=bhi((u4).z); f[6]=blo((u4).w); f[7]=bhi((u4).w); }

__global__ __launch_bounds__(1024, 4)
void fused_axial(const float* __restrict__ x,
                 const float* __restrict__ w_qkv,
                 const float* __restrict__ rel,
                 const float* __restrict__ bn_qkv,
                 const float* __restrict__ bn_sim,
                 const float* __restrict__ bn_out,
                 float* __restrict__ out) {
  constexpr float EPS = 1e-5f;
  __shared__ __align__(16) unsigned short qkv_t[64][264];  // [h][o] bf16 (528B rows)
  __shared__ __align__(16) unsigned short relC[127][40];   // [d][c] bf16 (80B rows)
                                                           // c<8: rel[c][d] (qr); 8..15: rel[c][126-d] (kr); 16..31: rel[c][d] (sve)
  __shared__ __align__(16) u32 UB[16384];                  // 64KB: xs[64][68] u32 | p[8][64][64] bf16 (XOR-swizzled)
  __shared__ float s_qkv[256], t_qkv[256], s_out[256], t_out[256], s_sim[24];

  const int bid = blockIdx.x;
  const int b = (bid & 7) * 128 + (bid >> 3);              // XCD-chunked swizzle (1024 % 8 == 0)
  const int n = b >> 6, w = b & 63;
  const int tid = threadIdx.x, wv = tid >> 6, lane = tid & 63;

  // ---- stage inputs ----
  const float* xb = x + n * 524288 + w;                    // x[n][c][h][w]
  for (int idx = tid; idx < 4096; idx += 1024) {
    const int h = idx & 63, cp = idx >> 6;                 // channel pair
    const float a0 = xb[(2 * cp) * 4096 + h * 64];
    const float a1 = xb[(2 * cp + 1) * 4096 + h * 64];
    UB[h * 68 + cp] = pk2(a0, a1);                         // xs[h][c] bf16
  }
  for (int idx = tid; idx < 4064; idx += 1024) {           // 127 * 32
    const int d = idx >> 5, c = idx & 31;
    const int rr = (c >= 8 && c < 16) ? (126 - d) : d;
    relC[d][c] = f2bf(rel[c * 127 + rr]);
  }
  if (tid < 256) {
    float ga = bn_qkv[tid], be = bn_qkv[256 + tid], mu = bn_qkv[512 + tid], va = bn_qkv[768 + tid];
    float s = ga * rsqrtf(va + EPS);
    s_qkv[tid] = s; t_qkv[tid] = be - mu * s;
    ga = bn_out[tid]; be = bn_out[256 + tid]; mu = bn_out[512 + tid]; va = bn_out[768 + tid];
    s = ga * rsqrtf(va + EPS);
    s_out[tid] = s; t_out[tid] = be - mu * s;
  } else if (tid < 280) {
    const int c = tid - 256;
    s_sim[c] = bn_sim[c] * rsqrtf(bn_sim[72 + c] + EPS);   // BN shift cancels in softmax
  }
  __syncthreads();

  // ---- P1: qkv_t[h][o] = BN(sum_c w[o][c] xs[h][c]); 16 outputs/wave, lane = h ----
  {
    const int o0 = __builtin_amdgcn_readfirstlane(wv) * 16;
    float acc[16];
    #pragma unroll
    for (int o = 0; o < 16; ++o) acc[o] = 0.f;
    const u32* xr = &UB[lane * 68];
    for (int cp = 0; cp < 64; cp += 4) {                   // 8 input channels / iter
      const uint4 xu = *reinterpret_cast<const uint4*>(xr + cp);
      float xf[8]; UNPK(xu, xf);
      const float* wp = w_qkv + o0 * 128 + cp * 2;         // wave-uniform -> s_load
      #pragma unroll
      for (int o = 0; o < 16; ++o) {
        const float4 wa = *reinterpret_cast<const float4*>(wp + o * 128);
        const float4 wb = *reinterpret_cast<const float4*>(wp + o * 128 + 4);
        acc[o] = fmaf(wa.x, xf[0], acc[o]); acc[o] = fmaf(wa.y, xf[1], acc[o]);
        acc[o] = fmaf(wa.z, xf[2], acc[o]); acc[o] = fmaf(wa.w, xf[3], acc[o]);
        acc[o] = fmaf(wb.x, xf[4], acc[o]); acc[o] = fmaf(wb.y, xf[5], acc[o]);
        acc[o] = fmaf(wb.z, xf[6], acc[o]); acc[o] = fmaf(wb.w, xf[7], acc[o]);
      }
    }
    u32* qrow = reinterpret_cast<u32*>(&qkv_t[lane][o0]);
    #pragma unroll
    for (int k = 0; k < 8; ++k) {
      const int oo = o0 + 2 * k;
      qrow[k] = pk2(s_qkv[oo] * acc[2 * k] + t_qkv[oo],
                    s_qkv[oo + 1] * acc[2 * k + 1] + t_qkv[oo + 1]);
    }
  }
  __syncthreads();

  const int g = wv & 7;                                    // group
  const int hh = wv >> 3;                                  // row-half (P3) / channel-half (P4)
  const int gc = g * 32;
  unsigned short* const pbuf = reinterpret_cast<unsigned short*>(UB);

  // ---- P3: e = exp(logit); lane = j, rows hh*32 .. hh*32+31 ----
  {
    const uint4 ku = *reinterpret_cast<const uint4*>(&qkv_t[lane][gc + 8]);
    float kf[8]; UNPK(ku, kf);
    const float sqk = s_sim[g], sqr = s_sim[8 + g], skr = s_sim[16 + g];
    for (int r = 0; r < 32; ++r) {
      const int i = hh * 32 + r;
      const uint4 qu = *reinterpret_cast<const uint4*>(&qkv_t[i][gc]);       // uniform
      const int d = i - lane + 63;                                           // 0..126
      const uint4 r1 = *reinterpret_cast<const uint4*>(&relC[d][0]);
      const uint4 r2 = *reinterpret_cast<const uint4*>(&relC[d][8]);
      float qf[8], ra[8], rb[8];
      UNPK(qu, qf); UNPK(r1, ra); UNPK(r2, rb);
      float qk = 0.f, qr = 0.f, kr = 0.f;
      #pragma unroll
      for (int c = 0; c < 8; ++c) {
        qk = fmaf(qf[c], kf[c], qk);
        qr = fmaf(qf[c], ra[c], qr);
        kr = fmaf(kf[c], rb[c], kr);
      }
      const float logit = fmaf(sqk, qk, fmaf(sqr, qr, skr * kr));
      pbuf[(g * 64 + i) * 64 + (lane ^ ((i & 7) << 3))] = f2bf(__expf(logit));
    }
  }
  __syncthreads();

  // ---- P4: sv/sve + denom; lane = i, 8 channels ch0..ch0+7 of group g ----
  {
    const int ch0 = hh * 8;
    float sv[8], se[8];
    #pragma unroll
    for (int k = 0; k < 8; ++k) { sv[k] = 0.f; se[k] = 0.f; }
    float psum = 0.f;
    const unsigned short* prow = pbuf + (g * 64 + lane) * 64;
    const int swz = (lane & 7) << 3;
    for (int j0 = 0; j0 < 64; j0 += 8) {
      const uint4 pu = *reinterpret_cast<const uint4*>(prow + (j0 ^ swz));
      float pf[8]; UNPK(pu, pf);
      psum += ((pf[0] + pf[1]) + (pf[2] + pf[3])) + ((pf[4] + pf[5]) + (pf[6] + pf[7]));
      #pragma unroll
      for (int jj = 0; jj < 8; ++jj) {
        const int j = j0 + jj;
        const uint4 vu = *reinterpret_cast<const uint4*>(&qkv_t[j][gc + 16 + ch0]);   // uniform
        const uint4 ru = *reinterpret_cast<const uint4*>(&relC[lane - j + 63][16 + ch0]);
        float vf[8], rf[8];
        UNPK(vu, vf); UNPK(ru, rf);
        const float pv = pf[jj];
        #pragma unroll
        for (int k = 0; k < 8; ++k) {
          sv[k] = fmaf(pv, vf[k], sv[k]);
          se[k] = fmaf(pv, rf[k], se[k]);
        }
      }
    }
    const float inv = 1.0f / psum;
    #pragma unroll
    for (int k = 0; k < 8; ++k) {
      const int p = g * 16 + ch0 + k;
      out[(n * 128 + p) * 4096 + lane * 64 + w] =                 // lockstep L2-combined
          fmaf(s_out[2 * p], inv * sv[k], t_out[2 * p])
        + fmaf(s_out[2 * p + 1], inv * se[k], t_out[2 * p + 1]);
    }
  }
}

extern "C" void kernel_launch(void* const* d_in, const int* in_sizes, int n_in,
                              void* d_out, int out_size, void* d_ws, size_t ws_size,
                              hipStream_t stream) {
  const float* x      = (const float*)d_in[0];
  const float* w_qkv  = (const float*)d_in[1];
  const float* rel    = (const float*)d_in[2];
  const float* bn_qkv = (const float*)d_in[3];
  const float* bn_sim = (const float*)d_in[4];
  const float* bn_out = (const float*)d_in[5];
  float* out = (float*)d_out;
  fused_axial<<<1024, 1024, 0, stream>>>(x, w_qkv, rel, bn_qkv, bn_sim, bn_out, out);
}

// Round 8
// 178.104 us; speedup vs baseline: 2.5892x; 2.5892x over previous
//
#include <hip/hip_runtime.h>

// Fused axial attention (RoadTransformer), bf16 LDS / fp32 compute.
// R8: P1 qkv-GEMM on MFMA (16x16x32 bf16). R3-proven residency restored:
//     512 threads, 1 block/CU (135 KB LDS), XCD swizzle, direct stores
//     (lockstep L2-combining: the only config with clean WRITE_SIZE).
//     P3/P4 identical to R4's verified code.

typedef unsigned int u32;
typedef __attribute__((ext_vector_type(8))) short short8;
typedef __attribute__((ext_vector_type(4))) float f32x4;

__device__ __forceinline__ float blo(u32 u) { return __uint_as_float(u << 16); }
__device__ __forceinline__ float bhi(u32 u) { return __uint_as_float(u & 0xffff0000u); }
__device__ __forceinline__ unsigned short f2bf(float f) {
  const u32 u = __float_as_uint(f);
  return (unsigned short)((u + 0x7fffu + ((u >> 16) & 1u)) >> 16);   // RNE
}
__device__ __forceinline__ u32 pk2(float a, float b) {
  return (u32)f2bf(a) | ((u32)f2bf(b) << 16);
}
#define UNPK(u4, f) { f[0]=blo((u4).x); f[1]=bhi((u4).x); f[2]=blo((u4).y); f[3]=bhi((u4).y); \
                      f[4]=blo((u4).z); f[5]=bhi((u4).z); f[6]=blo((u4).w); f[7]=bhi((u4).w); }

__global__ __launch_bounds__(512)
void fused_axial(const float* __restrict__ x,
                 const float* __restrict__ w_qkv,
                 const float* __restrict__ rel,
                 const float* __restrict__ bn_qkv,
                 const float* __restrict__ bn_sim,
                 const float* __restrict__ bn_out,
                 float* __restrict__ out) {
  constexpr float EPS = 1e-5f;
  // POOL: P1 = W_bf[256][136] bf16 (69632 B); P3/P4 = p[4][64][64] bf16 (32 KB)
  __shared__ __align__(16) u32 POOL[17408];
  __shared__ __align__(16) u32 XS[4352];                   // xs[64][136] bf16 rows (data c<128)
  __shared__ __align__(16) unsigned short qkv_t[64][264];  // [h][o] bf16 (528B rows)
  __shared__ __align__(16) unsigned short relC[127][40];   // [d][c] bf16
                                                           // c<8: rel[c][d]; 8..15: rel[c][126-d]; 16..31: rel[c][d]
  __shared__ float s_qkv[256], t_qkv[256], s_out[256], t_out[256], s_sim[24];
  // total ~135 KB -> 1 block/CU enforced

  const int bid = blockIdx.x;
  const int b = (bid & 7) * 128 + (bid >> 3);              // XCD-chunked swizzle (1024 % 8 == 0)
  const int n = b >> 6, w = b & 63;
  const int tid = threadIdx.x, wv = tid >> 6, lane = tid & 63;

  // ---- stage inputs ----
  const float* xb = x + n * 524288 + w;                    // x[n][c][h][w]
  for (int idx = tid; idx < 4096; idx += 512) {
    const int h = idx & 63, cp = idx >> 6;                 // channel pair
    const float a0 = xb[(2 * cp) * 4096 + h * 64];
    const float a1 = xb[(2 * cp + 1) * 4096 + h * 64];
    XS[h * 68 + cp] = pk2(a0, a1);                         // xs[h][c] bf16, row 68 u32
  }
  for (int idx = tid; idx < 16384; idx += 512) {           // W_bf[o][c] bf16, row 68 u32
    const int o = idx >> 6, cp = idx & 63;
    POOL[o * 68 + cp] = pk2(w_qkv[o * 128 + 2 * cp], w_qkv[o * 128 + 2 * cp + 1]);
  }
  for (int idx = tid; idx < 4064; idx += 512) {            // 127 * 32
    const int d = idx >> 5, c = idx & 31;
    const int rr = (c >= 8 && c < 16) ? (126 - d) : d;
    relC[d][c] = f2bf(rel[c * 127 + rr]);
  }
  if (tid < 256) {
    float ga = bn_qkv[tid], be = bn_qkv[256 + tid], mu = bn_qkv[512 + tid], va = bn_qkv[768 + tid];
    float s = ga * rsqrtf(va + EPS);
    s_qkv[tid] = s; t_qkv[tid] = be - mu * s;
    ga = bn_out[tid]; be = bn_out[256 + tid]; mu = bn_out[512 + tid]; va = bn_out[768 + tid];
    s = ga * rsqrtf(va + EPS);
    s_out[tid] = s; t_out[tid] = be - mu * s;
  } else if (tid < 280) {
    const int c = tid - 256;
    s_sim[c] = bn_sim[c] * rsqrtf(bn_sim[72 + c] + EPS);   // BN shift cancels in softmax
  }
  __syncthreads();

  // ---- P1 (MFMA): qkv_t[h][o] = BN( xs(64x128) . W^T(128x256) ) ----
  // D = A.B: A[m][k]=xs[h][c], B[k][n]=W[o][c] (W^T). Lane l=16q+p:
  //   A-frag elem j = A[p][8q+j]; B-frag elem j = B[8q+j][p]; D reg r = D[4q+r][p].
  {
    const int q = lane >> 4, p = lane & 15;
    const unsigned short* xsb = reinterpret_cast<const unsigned short*>(XS);
    const unsigned short* wb  = reinterpret_cast<const unsigned short*>(POOL);
    short8 af[4][4];
    #pragma unroll
    for (int ht = 0; ht < 4; ++ht)
      #pragma unroll
      for (int kk = 0; kk < 4; ++kk)
        af[ht][kk] = *reinterpret_cast<const short8*>(&xsb[(ht * 16 + p) * 136 + kk * 32 + q * 8]);
    #pragma unroll
    for (int t = 0; t < 2; ++t) {
      const int o = (wv * 2 + t) * 16 + p;
      short8 bf[4];
      #pragma unroll
      for (int kk = 0; kk < 4; ++kk)
        bf[kk] = *reinterpret_cast<const short8*>(&wb[o * 136 + kk * 32 + q * 8]);
      const float sq = s_qkv[o], tq = t_qkv[o];
      #pragma unroll
      for (int ht = 0; ht < 4; ++ht) {
        f32x4 acc = {0.f, 0.f, 0.f, 0.f};
        #pragma unroll
        for (int kk = 0; kk < 4; ++kk)
          acc = __builtin_amdgcn_mfma_f32_16x16x32_bf16(af[ht][kk], bf[kk], acc, 0, 0, 0);
        #pragma unroll
        for (int r = 0; r < 4; ++r)
          qkv_t[ht * 16 + q * 4 + r][o] = f2bf(sq * acc[r] + tq);
      }
    }
  }
  __syncthreads();

  const int g_l = wv & 3;                                  // group within pass
  const int hh = wv >> 2;                                  // row-half (P3) / channel-half (P4)
  unsigned short* const pbuf = reinterpret_cast<unsigned short*>(POOL);

  for (int pass = 0; pass < 2; ++pass) {
    const int g = pass * 4 + g_l;
    const int gc = g * 32;

    // ---- P3: e = exp(logit); lane = j, rows hh*32 .. hh*32+31 ----
    {
      const uint4 ku = *reinterpret_cast<const uint4*>(&qkv_t[lane][gc + 8]);
      float kf[8]; UNPK(ku, kf);
      const float sqk = s_sim[g], sqr = s_sim[8 + g], skr = s_sim[16 + g];
      for (int r = 0; r < 32; ++r) {
        const int i = hh * 32 + r;
        const uint4 qu = *reinterpret_cast<const uint4*>(&qkv_t[i][gc]);     // uniform
        const int d = i - lane + 63;                                         // 0..126
        const uint4 r1 = *reinterpret_cast<const uint4*>(&relC[d][0]);
        const uint4 r2 = *reinterpret_cast<const uint4*>(&relC[d][8]);
        float qf[8], ra[8], rb[8];
        UNPK(qu, qf); UNPK(r1, ra); UNPK(r2, rb);
        float qk = 0.f, qr = 0.f, kr = 0.f;
        #pragma unroll
        for (int c = 0; c < 8; ++c) {
          qk = fmaf(qf[c], kf[c], qk);
          qr = fmaf(qf[c], ra[c], qr);
          kr = fmaf(kf[c], rb[c], kr);
        }
        const float logit = fmaf(sqk, qk, fmaf(sqr, qr, skr * kr));
        pbuf[(g_l * 64 + i) * 64 + (lane ^ ((i & 7) << 3))] = f2bf(__expf(logit));
      }
    }
    __syncthreads();

    // ---- P4: sv/sve + denom; lane = i, 8 channels ch0..ch0+7 of group g ----
    {
      const int ch0 = hh * 8;
      float sv[8], se[8];
      #pragma unroll
      for (int k = 0; k < 8; ++k) { sv[k] = 0.f; se[k] = 0.f; }
      float psum = 0.f;
      const unsigned short* prow = pbuf + (g_l * 64 + lane) * 64;
      const int swz = (lane & 7) << 3;
      for (int j0 = 0; j0 < 64; j0 += 8) {
        const uint4 pu = *reinterpret_cast<const uint4*>(prow + (j0 ^ swz));
        float pf[8]; UNPK(pu, pf);
        psum += ((pf[0] + pf[1]) + (pf[2] + pf[3])) + ((pf[4] + pf[5]) + (pf[6] + pf[7]));
        #pragma unroll
        for (int jj = 0; jj < 8; ++jj) {
          const int j = j0 + jj;
          const uint4 vu = *reinterpret_cast<const uint4*>(&qkv_t[j][gc + 16 + ch0]); // uniform
          const uint4 ru = *reinterpret_cast<const uint4*>(&relC[lane - j + 63][16 + ch0]);
          float vf[8], rf[8];
          UNPK(vu, vf); UNPK(ru, rf);
          const float pv = pf[jj];
          #pragma unroll
          for (int k = 0; k < 8; ++k) {
            sv[k] = fmaf(pv, vf[k], sv[k]);
            se[k] = fmaf(pv, rf[k], se[k]);
          }
        }
      }
      const float inv = 1.0f / psum;
      #pragma unroll
      for (int k = 0; k < 8; ++k) {
        const int p = g * 16 + ch0 + k;
        out[(n * 128 + p) * 4096 + lane * 64 + w] =              // lockstep L2-combined
            fmaf(s_out[2 * p], inv * sv[k], t_out[2 * p])
          + fmaf(s_out[2 * p + 1], inv * se[k], t_out[2 * p + 1]);
      }
    }
    __syncthreads();
  }
}

extern "C" void kernel_launch(void* const* d_in, const int* in_sizes, int n_in,
                              void* d_out, int out_size, void* d_ws, size_t ws_size,
                              hipStream_t stream) {
  const float* x      = (const float*)d_in[0];
  const float* w_qkv  = (const float*)d_in[1];
  const float* rel    = (const float*)d_in[2];
  const float* bn_qkv = (const float*)d_in[3];
  const float* bn_sim = (const float*)d_in[4];
  const float* bn_out = (const float*)d_in[5];
  float* out = (float*)d_out;
  fused_axial<<<1024, 512, 0, stream>>>(x, w_qkv, rel, bn_qkv, bn_sim, bn_out, out);
}

// Round 9
// 138.894 us; speedup vs baseline: 3.3202x; 1.2823x over previous
//
#include <hip/hip_runtime.h>

// Fused axial attention (RoadTransformer), bf16 LDS / fp32 compute.
// R9: P4 fully on MFMA: sv = P.V^T (K=64); sve via SKEWED p-copy
//     p~[i][t]=p[i][j], t=i+63-j  ->  sve[i][c] = sum_t p~[i][t] relV[c][t]
//     (K=128 GEMM, zeros outside [i,i+63], zero-inited ONCE); psum via
//     B=ones MFMA. P1 also emits v_t[g][c][j] (transposed V) from its t=1
//     tile. R3/R8-proven residency: 512 thr, 1 blk/CU, XCD swizzle.

typedef unsigned int u32;
typedef __attribute__((ext_vector_type(8))) short short8;
typedef __attribute__((ext_vector_type(4))) float f32x4;

__device__ __forceinline__ float blo(u32 u) { return __uint_as_float(u << 16); }
__device__ __forceinline__ float bhi(u32 u) { return __uint_as_float(u & 0xffff0000u); }
__device__ __forceinline__ unsigned short f2bf(float f) {
  const u32 u = __float_as_uint(f);
  return (unsigned short)((u + 0x7fffu + ((u >> 16) & 1u)) >> 16);   // RNE
}
__device__ __forceinline__ u32 pk2(float a, float b) {
  return (u32)f2bf(a) | ((u32)f2bf(b) << 16);
}
#define UNPK(u4, f) { f[0]=blo((u4).x); f[1]=bhi((u4).x); f[2]=blo((u4).y); f[3]=bhi((u4).y); \
                      f[4]=blo((u4).z); f[5]=bhi((u4).z); f[6]=blo((u4).w); f[7]=bhi((u4).w); }

__global__ __launch_bounds__(512)
void fused_axial(const float* __restrict__ x,
                 const float* __restrict__ w_qkv,
                 const float* __restrict__ rel,
                 const float* __restrict__ bn_qkv,
                 const float* __restrict__ bn_sim,
                 const float* __restrict__ bn_out,
                 float* __restrict__ out) {
  constexpr float EPS = 1e-5f;
  // POOL: P1 = W_bf[256][136]ush (69632 B). Passes: p_n[2][64][80]ush (u32 [0,5120))
  //       + p_s[2][64][144]ush (u32 [5120,14336)).
  __shared__ __align__(16) u32 POOL[17408];
  // XS: P1 = xs[64][136]ush; after P1 = v_t[8][16][72]ush (18432 B)
  __shared__ __align__(16) u32 XS[4608];
  __shared__ __align__(16) unsigned short qkv_t[64][264];  // [h][o] bf16 (528B rows)
  __shared__ __align__(16) unsigned short relCf[127 * 24]; // [d][c<16]: c<8 rel[c][d] (qr), 8..15 rel[c][126-d] (kr)
  __shared__ __align__(16) unsigned short relVm[16 * 144]; // [c][t]: rel[16+c][t], t<127, else 0
  __shared__ float s_qkv[256], t_qkv[256], s_out[256], t_out[256], s_sim[24];

  const int bid = blockIdx.x;
  const int b = (bid & 7) * 128 + (bid >> 3);              // XCD-chunked swizzle
  const int n = b >> 6, w = b & 63;
  const int tid = threadIdx.x, wv = tid >> 6, lane = tid & 63;

  // ---- stage inputs ----
  const float* xb = x + n * 524288 + w;                    // x[n][c][h][w]
  {
    unsigned short* xsb = reinterpret_cast<unsigned short*>(XS);
    for (int idx = tid; idx < 4096; idx += 512) {
      const int h = idx & 63, cp = idx >> 6;
      const float a0 = xb[(2 * cp) * 4096 + h * 64];
      const float a1 = xb[(2 * cp + 1) * 4096 + h * 64];
      *reinterpret_cast<u32*>(&xsb[h * 136 + 2 * cp]) = pk2(a0, a1);
    }
  }
  for (int idx = tid; idx < 16384; idx += 512) {           // W_bf[o][c], row 68 u32
    const int o = idx >> 6, cp = idx & 63;
    POOL[o * 68 + cp] = pk2(w_qkv[o * 128 + 2 * cp], w_qkv[o * 128 + 2 * cp + 1]);
  }
  for (int idx = tid; idx < 2032; idx += 512) {            // 127*16
    const int d = idx >> 4, c = idx & 15;
    const int rr = (c >= 8) ? (126 - d) : d;
    relCf[d * 24 + c] = f2bf(rel[c * 127 + rr]);
  }
  for (int idx = tid; idx < 2304; idx += 512) {            // 16*144
    const int c = idx / 144, t = idx % 144;
    relVm[idx] = (t < 127) ? f2bf(rel[(16 + c) * 127 + t]) : (unsigned short)0;
  }
  if (tid < 256) {
    float ga = bn_qkv[tid], be = bn_qkv[256 + tid], mu = bn_qkv[512 + tid], va = bn_qkv[768 + tid];
    float s = ga * rsqrtf(va + EPS);
    s_qkv[tid] = s; t_qkv[tid] = be - mu * s;
    ga = bn_out[tid]; be = bn_out[256 + tid]; mu = bn_out[512 + tid]; va = bn_out[768 + tid];
    s = ga * rsqrtf(va + EPS);
    s_out[tid] = s; t_out[tid] = be - mu * s;
  } else if (tid < 280) {
    const int c = tid - 256;
    s_sim[c] = bn_sim[c] * rsqrtf(bn_sim[72 + c] + EPS);   // BN shift cancels in softmax
  }
  __syncthreads();

  const int fq = lane >> 4, fp = lane & 15;                // MFMA lane coords

  // ---- P1 (MFMA): qkv_t[h][o] = BN(xs(64x128).W^T); also v_t[g][c][j] from t=1 tile ----
  {
    const unsigned short* xsb = reinterpret_cast<const unsigned short*>(XS);
    short8 af[4][4];
    #pragma unroll
    for (int ht = 0; ht < 4; ++ht)
      #pragma unroll
      for (int kk = 0; kk < 4; ++kk)
        af[ht][kk] = *reinterpret_cast<const short8*>(&xsb[(ht * 16 + fp) * 136 + kk * 32 + fq * 8]);
    __syncthreads();                                       // all xs reads done before v_t writes
    const unsigned short* wb = reinterpret_cast<const unsigned short*>(POOL);
    unsigned short* vt = reinterpret_cast<unsigned short*>(XS);
    #pragma unroll
    for (int t = 0; t < 2; ++t) {
      const int o = (wv * 2 + t) * 16 + fp;
      short8 bf[4];
      #pragma unroll
      for (int kk = 0; kk < 4; ++kk)
        bf[kk] = *reinterpret_cast<const short8*>(&wb[o * 136 + kk * 32 + fq * 8]);
      const float sq = s_qkv[o], tq = t_qkv[o];
      #pragma unroll
      for (int ht = 0; ht < 4; ++ht) {
        f32x4 acc = {0.f, 0.f, 0.f, 0.f};
        #pragma unroll
        for (int kk = 0; kk < 4; ++kk)
          acc = __builtin_amdgcn_mfma_f32_16x16x32_bf16(af[ht][kk], bf[kk], acc, 0, 0, 0);
        unsigned short e[4];
        #pragma unroll
        for (int r = 0; r < 4; ++r) {
          e[r] = f2bf(sq * acc[r] + tq);
          qkv_t[ht * 16 + fq * 4 + r][o] = e[r];
        }
        if (t == 1) {                                      // v-channels: c = fp, group = wv
          const u32 lo = (u32)e[0] | ((u32)e[1] << 16);
          const u32 hi = (u32)e[2] | ((u32)e[3] << 16);
          uint2 pr; pr.x = lo; pr.y = hi;
          *reinterpret_cast<uint2*>(&vt[(wv * 16 + fp) * 72 + ht * 16 + 4 * fq]) = pr;
        }
      }
    }
  }
  __syncthreads();

  // ---- zero-init skewed p buffer ONCE (valid region is pass-invariant) ----
  {
    uint4 z; z.x = 0; z.y = 0; z.z = 0; z.w = 0;
    uint4* pz = reinterpret_cast<uint4*>(POOL + 5120);
    for (int idx = tid; idx < 2304; idx += 512) pz[idx] = z;  // 2*64*144 ush
  }
  __syncthreads();

  unsigned short* const pn = reinterpret_cast<unsigned short*>(POOL);
  unsigned short* const ps = reinterpret_cast<unsigned short*>(POOL + 5120);
  const unsigned short* const vt = reinterpret_cast<const unsigned short*>(XS);

  short8 onev;
  { const short o1 = (short)0x3F80;                        // bf16 1.0
    onev[0]=o1; onev[1]=o1; onev[2]=o1; onev[3]=o1; onev[4]=o1; onev[5]=o1; onev[6]=o1; onev[7]=o1; }

  for (int pass = 0; pass < 4; ++pass) {
    // ---- P3: e = exp(logit); wave -> (group-slot wv>>2, rows (wv&3)*16..+15), lane = j ----
    {
      const int g2 = wv >> 2;
      const int g = pass * 2 + g2, gc = g * 32;
      const uint4 ku = *reinterpret_cast<const uint4*>(&qkv_t[lane][gc + 8]);
      float kf[8]; UNPK(ku, kf);
      const float sqk = s_sim[g], sqr = s_sim[8 + g], skr = s_sim[16 + g];
      #pragma unroll 4
      for (int r = 0; r < 16; ++r) {
        const int i = (wv & 3) * 16 + r;
        const uint4 qu = *reinterpret_cast<const uint4*>(&qkv_t[i][gc]);     // uniform
        const int d = i - lane + 63;                                         // 0..126
        const uint4 r1 = *reinterpret_cast<const uint4*>(&relCf[d * 24]);
        const uint4 r2 = *reinterpret_cast<const uint4*>(&relCf[d * 24 + 8]);
        float qf[8], ra[8], rb[8];
        UNPK(qu, qf); UNPK(r1, ra); UNPK(r2, rb);
        float qk = 0.f, qr = 0.f, kr = 0.f;
        #pragma unroll
        for (int c = 0; c < 8; ++c) {
          qk = fmaf(qf[c], kf[c], qk);
          qr = fmaf(qf[c], ra[c], qr);
          kr = fmaf(kf[c], rb[c], kr);
        }
        const float logit = fmaf(sqk, qk, fmaf(sqr, qr, skr * kr));
        const unsigned short eb = f2bf(__expf(logit));
        pn[(g2 * 64 + i) * 80 + lane] = eb;                // normal  p[i][j]
        ps[(g2 * 64 + i) * 144 + (i + 63 - lane)] = eb;    // skewed  p~[i][t]
      }
    }
    __syncthreads();

    // ---- P4 (MFMA): wave -> (g2 = wv>>2, m-tile mt = wv&3) ----
    {
      const int g2 = wv >> 2, mt = wv & 3;
      const int g = pass * 2 + g2;
      const unsigned short* pnb = &pn[(g2 * 64 + mt * 16 + fp) * 80];
      const unsigned short* psb = &ps[(g2 * 64 + mt * 16 + fp) * 144];
      const short8 an0 = *reinterpret_cast<const short8*>(&pnb[fq * 8]);
      const short8 an1 = *reinterpret_cast<const short8*>(&pnb[32 + fq * 8]);
      f32x4 sv = {0.f, 0.f, 0.f, 0.f}, se = sv, psm = sv;
      {
        const unsigned short* vtb = &vt[(g * 16 + fp) * 72];
        const short8 bv0 = *reinterpret_cast<const short8*>(&vtb[fq * 8]);
        const short8 bv1 = *reinterpret_cast<const short8*>(&vtb[32 + fq * 8]);
        sv = __builtin_amdgcn_mfma_f32_16x16x32_bf16(an0, bv0, sv, 0, 0, 0);
        sv = __builtin_amdgcn_mfma_f32_16x16x32_bf16(an1, bv1, sv, 0, 0, 0);
      }
      psm = __builtin_amdgcn_mfma_f32_16x16x32_bf16(an0, onev, psm, 0, 0, 0);
      psm = __builtin_amdgcn_mfma_f32_16x16x32_bf16(an1, onev, psm, 0, 0, 0);
      #pragma unroll
      for (int kk = 0; kk < 4; ++kk) {
        const short8 as = *reinterpret_cast<const short8*>(&psb[kk * 32 + fq * 8]);
        const short8 br = *reinterpret_cast<const short8*>(&relVm[fp * 144 + kk * 32 + fq * 8]);
        se = __builtin_amdgcn_mfma_f32_16x16x32_bf16(as, br, se, 0, 0, 0);
      }
      const int P = g * 16 + fp;
      const float so0 = s_out[2 * P], to0 = t_out[2 * P];
      const float so1 = s_out[2 * P + 1], to1 = t_out[2 * P + 1];
      #pragma unroll
      for (int r = 0; r < 4; ++r) {
        const float inv = 1.0f / psm[r];
        const int i = mt * 16 + 4 * fq + r;
        out[(n * 128 + P) * 4096 + i * 64 + w] =
            fmaf(so0, sv[r] * inv, to0) + fmaf(so1, se[r] * inv, to1);
      }
    }
    __syncthreads();
  }
}

extern "C" void kernel_launch(void* const* d_in, const int* in_sizes, int n_in,
                              void* d_out, int out_size, void* d_ws, size_t ws_size,
                              hipStream_t stream) {
  const float* x      = (const float*)d_in[0];
  const float* w_qkv  = (const float*)d_in[1];
  const float* rel    = (const float*)d_in[2];
  const float* bn_qkv = (const float*)d_in[3];
  const float* bn_sim = (const float*)d_in[4];
  const float* bn_out = (const float*)d_in[5];
  float* out = (float*)d_out;
  fused_axial<<<1024, 512, 0, stream>>>(x, w_qkv, rel, bn_qkv, bn_sim, bn_out, out);
}

// Round 10
// 107.030 us; speedup vs baseline: 4.3086x; 1.2977x over previous
//
#include <hip/hip_runtime.h>

// Fused axial attention (RoadTransformer), bf16 LDS / fp32 compute.
// R10: 2 blocks/CU (4 waves/SIMD). LDS trimmed to 81472 B (=80KiB rounded):
//   - 1-group passes (8 passes): pn[64][72], skewed ps[64][96] m-tile-local
//   - W MFMA B-frags loaded from GLOBAL f32 + v_cvt_pk_bf16_f32 (no W stage)
//   - BN affine params read from global in epilogues (no scalar LDS arrays)
//   - launch_bounds(512,2): VGPR cap 128 (R4-7's 1GB traffic was the 64-VGPR
//     spill from min-blocks=4, NOT store-combining; stores combine via swizzle)
// Phase math identical to R9 (P1 MFMA qkv, P3 VALU logits, P4 MFMA sv/sve).

typedef unsigned int u32;
typedef __attribute__((ext_vector_type(8))) short short8;
typedef __attribute__((ext_vector_type(4))) float f32x4;

__device__ __forceinline__ float blo(u32 u) { return __uint_as_float(u << 16); }
__device__ __forceinline__ float bhi(u32 u) { return __uint_as_float(u & 0xffff0000u); }
__device__ __forceinline__ unsigned short f2bf(float f) {
  const u32 u = __float_as_uint(f);
  return (unsigned short)((u + 0x7fffu + ((u >> 16) & 1u)) >> 16);   // RNE
}
__device__ __forceinline__ u32 pk2(float a, float b) {
  return (u32)f2bf(a) | ((u32)f2bf(b) << 16);
}
__device__ __forceinline__ u32 cvtpk(float lo, float hi) {          // RNE, 1 inst
  u32 d; asm("v_cvt_pk_bf16_f32 %0, %1, %2" : "=v"(d) : "v"(lo), "v"(hi)); return d;
}
#define UNPK(u4, f) { f[0]=blo((u4).x); f[1]=bhi((u4).x); f[2]=blo((u4).y); f[3]=bhi((u4).y); \
                      f[4]=blo((u4).z); f[5]=bhi((u4).z); f[6]=blo((u4).w); f[7]=bhi((u4).w); }

__global__ __launch_bounds__(512, 2)
void fused_axial(const float* __restrict__ x,
                 const float* __restrict__ w_qkv,
                 const float* __restrict__ rel,
                 const float* __restrict__ bn_qkv,
                 const float* __restrict__ bn_sim,
                 const float* __restrict__ bn_out,
                 float* __restrict__ out) {
  constexpr float EPS = 1e-5f;
  __shared__ __align__(16) u32 XS[4352];                   // xs[64][68]u32 | vt[8][16][64]ush
  __shared__ __align__(16) unsigned short qkv_t[64][264];  // [h][o] bf16 (528B rows)
  __shared__ __align__(16) unsigned short pn[64 * 72];     // p normal, row stride 72
  __shared__ __align__(16) unsigned short ps[64 * 96];     // p skewed (m-tile-local t), stride 96
  __shared__ __align__(16) unsigned short relCf[127 * 16]; // [d][c]: c<8 rel[c][d]; 8..15 rel[c][126-d]
  __shared__ __align__(16) unsigned short relVm[16 * 144]; // [c][t]: rel[16+c][t], t<127 else 0
  __shared__ float s_sim[24];
  // total 81472 B -> 80 KiB -> 2 blocks/CU

  const int bid = blockIdx.x;
  const int b = (bid & 7) * 128 + (bid >> 3);              // XCD-chunked swizzle (1024 % 8 == 0)
  const int n = b >> 6, w = b & 63;
  const int tid = threadIdx.x, wv = tid >> 6, lane = tid & 63;
  const int fq = lane >> 4, fp = lane & 15;                // MFMA lane coords

  // ---- stage inputs ----
  const float* xb = x + n * 524288 + w;                    // x[n][c][h][w]
  {
    unsigned short* xsb = reinterpret_cast<unsigned short*>(XS);
    for (int idx = tid; idx < 4096; idx += 512) {
      const int h = idx & 63, cp = idx >> 6;
      const float a0 = xb[(2 * cp) * 4096 + h * 64];
      const float a1 = xb[(2 * cp + 1) * 4096 + h * 64];
      *reinterpret_cast<u32*>(&xsb[h * 136 + 2 * cp]) = pk2(a0, a1);
    }
  }
  for (int idx = tid; idx < 2032; idx += 512) {            // 127*16
    const int d = idx >> 4, c = idx & 15;
    relCf[d * 16 + c] = f2bf(rel[c * 127 + ((c >= 8) ? (126 - d) : d)]);
  }
  for (int idx = tid; idx < 2304; idx += 512) {            // 16*144
    const int c = idx / 144, t = idx % 144;
    relVm[idx] = (t < 127) ? f2bf(rel[(16 + c) * 127 + t]) : (unsigned short)0;
  }
  {
    uint4 z; z.x = 0; z.y = 0; z.z = 0; z.w = 0;
    uint4* pz = reinterpret_cast<uint4*>(ps);
    for (int idx = tid; idx < 768; idx += 512) pz[idx] = z;  // zero skewed buf ONCE
  }
  if (tid < 24) s_sim[tid] = bn_sim[tid] * rsqrtf(bn_sim[72 + tid] + EPS);
  __syncthreads();

  // ---- P1 (MFMA): qkv_t[h][o] = BN(xs(64x128).W^T); v_t[g][c][j] from odd o-tiles ----
  {
    const unsigned short* xsb = reinterpret_cast<const unsigned short*>(XS);
    short8 af[4][4];
    #pragma unroll
    for (int ht = 0; ht < 4; ++ht)
      #pragma unroll
      for (int kk = 0; kk < 4; ++kk)
        af[ht][kk] = *reinterpret_cast<const short8*>(&xsb[(ht * 16 + fp) * 136 + kk * 32 + fq * 8]);
    __syncthreads();                                       // xs reads done before vt writes
    unsigned short* vt = reinterpret_cast<unsigned short*>(XS);
    #pragma unroll
    for (int t = 0; t < 2; ++t) {
      const int ot = wv * 2 + t;
      const int o = ot * 16 + fp;
      short8 bf[4];
      #pragma unroll
      for (int kk = 0; kk < 4; ++kk) {                     // W frag from global f32
        const float* wp = w_qkv + o * 128 + kk * 32 + fq * 8;
        const float4 lo4 = *reinterpret_cast<const float4*>(wp);
        const float4 hi4 = *reinterpret_cast<const float4*>(wp + 4);
        union { u32 u[4]; short8 s; } uu;
        uu.u[0] = cvtpk(lo4.x, lo4.y); uu.u[1] = cvtpk(lo4.z, lo4.w);
        uu.u[2] = cvtpk(hi4.x, hi4.y); uu.u[3] = cvtpk(hi4.z, hi4.w);
        bf[kk] = uu.s;
      }
      const float ga = bn_qkv[o], be = bn_qkv[256 + o], mu = bn_qkv[512 + o], va = bn_qkv[768 + o];
      const float sq = ga * rsqrtf(va + EPS), tq = be - mu * sq;
      #pragma unroll
      for (int ht = 0; ht < 4; ++ht) {
        f32x4 acc = {0.f, 0.f, 0.f, 0.f};
        #pragma unroll
        for (int kk = 0; kk < 4; ++kk)
          acc = __builtin_amdgcn_mfma_f32_16x16x32_bf16(af[ht][kk], bf[kk], acc, 0, 0, 0);
        unsigned short e[4];
        #pragma unroll
        for (int r = 0; r < 4; ++r) {
          e[r] = f2bf(sq * acc[r] + tq);
          qkv_t[ht * 16 + fq * 4 + r][o] = e[r];
        }
        if (t == 1) {                                      // V-channels: group ot>>1, c = fp
          uint2 pr;
          pr.x = (u32)e[0] | ((u32)e[1] << 16);
          pr.y = (u32)e[2] | ((u32)e[3] << 16);
          *reinterpret_cast<uint2*>(&vt[((ot >> 1) * 16 + fp) * 64 + ht * 16 + 4 * fq]) = pr;
        }
      }
    }
  }
  __syncthreads();

  short8 onev;
  { const short o1 = (short)0x3F80;                        // bf16 1.0
    onev[0]=o1; onev[1]=o1; onev[2]=o1; onev[3]=o1; onev[4]=o1; onev[5]=o1; onev[6]=o1; onev[7]=o1; }

  for (int g = 0; g < 8; ++g) {
    const int gc = g * 32;

    // ---- P3: e = exp(logit); wave wv -> rows wv*8..wv*8+7, lane = j ----
    {
      const uint4 ku = *reinterpret_cast<const uint4*>(&qkv_t[lane][gc + 8]);
      float kf[8]; UNPK(ku, kf);
      const float sqk = s_sim[g], sqr = s_sim[8 + g], skr = s_sim[16 + g];
      #pragma unroll
      for (int r = 0; r < 8; ++r) {
        const int i = wv * 8 + r;
        const uint4 qu = *reinterpret_cast<const uint4*>(&qkv_t[i][gc]);     // uniform
        const int d = i - lane + 63;                                         // 0..126
        const uint4 r1 = *reinterpret_cast<const uint4*>(&relCf[d * 16]);
        const uint4 r2 = *reinterpret_cast<const uint4*>(&relCf[d * 16 + 8]);
        float qf[8], ra[8], rb[8];
        UNPK(qu, qf); UNPK(r1, ra); UNPK(r2, rb);
        float qk = 0.f, qr = 0.f, kr = 0.f;
        #pragma unroll
        for (int c = 0; c < 8; ++c) {
          qk = fmaf(qf[c], kf[c], qk);
          qr = fmaf(qf[c], ra[c], qr);
          kr = fmaf(kf[c], rb[c], kr);
        }
        const float logit = fmaf(sqk, qk, fmaf(sqr, qr, skr * kr));
        const unsigned short eb = f2bf(__expf(logit));
        pn[i * 72 + lane] = eb;                            // normal p[i][j]
        ps[i * 96 + (i & 15) + 63 - lane] = eb;            // skewed, m-tile-local t
      }
    }
    __syncthreads();

    // ---- P4 (MFMA): waves 0-3, mt = wv ----
    if (wv < 4) {
      const int mt = wv;
      const unsigned short* pnb = &pn[(mt * 16 + fp) * 72];
      const unsigned short* psb = &ps[(mt * 16 + fp) * 96];
      const unsigned short* vtb = reinterpret_cast<const unsigned short*>(XS) + (g * 16 + fp) * 64;
      const short8 an0 = *reinterpret_cast<const short8*>(&pnb[fq * 8]);
      const short8 an1 = *reinterpret_cast<const short8*>(&pnb[32 + fq * 8]);
      f32x4 sv = {0.f, 0.f, 0.f, 0.f}, se = sv, psm = sv;
      {
        const short8 bv0 = *reinterpret_cast<const short8*>(&vtb[fq * 8]);
        const short8 bv1 = *reinterpret_cast<const short8*>(&vtb[32 + fq * 8]);
        sv = __builtin_amdgcn_mfma_f32_16x16x32_bf16(an0, bv0, sv, 0, 0, 0);
        sv = __builtin_amdgcn_mfma_f32_16x16x32_bf16(an1, bv1, sv, 0, 0, 0);
      }
      psm = __builtin_amdgcn_mfma_f32_16x16x32_bf16(an0, onev, psm, 0, 0, 0);
      psm = __builtin_amdgcn_mfma_f32_16x16x32_bf16(an1, onev, psm, 0, 0, 0);
      #pragma unroll
      for (int kk = 0; kk < 3; ++kk) {                     // K=96 m-tile-local skew
        const short8 as = *reinterpret_cast<const short8*>(&psb[kk * 32 + fq * 8]);
        const short8 br = *reinterpret_cast<const short8*>(&relVm[fp * 144 + mt * 16 + kk * 32 + fq * 8]);
        se = __builtin_amdgcn_mfma_f32_16x16x32_bf16(as, br, se, 0, 0, 0);
      }
      const int P = g * 16 + fp;
      const float2 ga2 = *reinterpret_cast<const float2*>(&bn_out[2 * P]);
      const float2 be2 = *reinterpret_cast<const float2*>(&bn_out[256 + 2 * P]);
      const float2 mu2 = *reinterpret_cast<const float2*>(&bn_out[512 + 2 * P]);
      const float2 va2 = *reinterpret_cast<const float2*>(&bn_out[768 + 2 * P]);
      const float so0 = ga2.x * rsqrtf(va2.x + EPS), to0 = be2.x - mu2.x * so0;
      const float so1 = ga2.y * rsqrtf(va2.y + EPS), to1 = be2.y - mu2.y * so1;
      #pragma unroll
      for (int r = 0; r < 4; ++r) {
        const float inv = 1.0f / psm[r];
        const int i = mt * 16 + 4 * fq + r;
        out[(n * 128 + P) * 4096 + i * 64 + w] =
            fmaf(so0, sv[r] * inv, to0) + fmaf(so1, se[r] * inv, to1);
      }
    }
    __syncthreads();
  }
}

extern "C" void kernel_launch(void* const* d_in, const int* in_sizes, int n_in,
                              void* d_out, int out_size, void* d_ws, size_t ws_size,
                              hipStream_t stream) {
  const float* x      = (const float*)d_in[0];
  const float* w_qkv  = (const float*)d_in[1];
  const float* rel    = (const float*)d_in[2];
  const float* bn_qkv = (const float*)d_in[3];
  const float* bn_sim = (const float*)d_in[4];
  const float* bn_out = (const float*)d_in[5];
  float* out = (float*)d_out;
  fused_axial<<<1024, 512, 0, stream>>>(x, w_qkv, rel, bn_qkv, bn_sim, bn_out, out);
}